// Round 1
// baseline (481.836 us; speedup 1.0000x reference)
//
#include <hip/hip_runtime.h>
#include <math.h>

#define M_TOTAL 16384
#define DDIM    4096
#define EXP     64
#define BM      64
#define BK      32
#define SA      68   // LDS row stride (words) for As[k][m], padded: conflict-free b128 reads
#define SW      68   // LDS row stride for Ws[k][e]

// GEMM: part[slice][row][e] = sum_k A[row][k] * Bw[k][e]
// slice 0: x @ weight ; slice 1: noise @ noise_weight
__global__ __launch_bounds__(256) void router_gemm(
    const float* __restrict__ x, const float* __restrict__ noise,
    const float* __restrict__ w, const float* __restrict__ nw,
    float* __restrict__ part)
{
    __shared__ float As[BK * SA];
    __shared__ float Ws[BK * SW];

    const int slice = blockIdx.y;
    const float* __restrict__ A  = slice ? noise : x;
    const float* __restrict__ Bw = slice ? nw    : w;
    float* __restrict__ out = part + (size_t)slice * M_TOTAL * EXP;

    const int tid = threadIdx.x;
    const int ty  = tid >> 4;   // 0..15 row group (4 rows each)
    const int tx  = tid & 15;   // 0..15 col group (4 cols each)
    const int rowBase = blockIdx.x * BM;

    // loader mappings
    const int lm  = tid >> 2;   // 0..63: row within tile (A loader)
    const int lkq = tid & 3;    // 0..3 : k-quad (A loader)
    const int wkr = tid >> 4;   // 0..15: k row (W loader)
    const int weq = tid & 15;   // 0..15: e-quad (W loader)

    double acc[4][4];
#pragma unroll
    for (int i = 0; i < 4; ++i)
#pragma unroll
        for (int j = 0; j < 4; ++j) acc[i][j] = 0.0;

    const float* __restrict__ aRow = A + (size_t)(rowBase + lm) * DDIM;

    for (int kt = 0; kt < DDIM / BK; ++kt) {
        const int k0 = kt * BK;

        // ---- stage A tile: As[k][m], k-major; global reads coalesced (64B/row-chunk)
#pragma unroll
        for (int i = 0; i < 2; ++i) {
            const int kloc = 4 * lkq + 16 * i;      // 0..31
            const float4 a4 = *(const float4*)(aRow + k0 + kloc);
            As[(kloc + 0) * SA + lm] = a4.x;
            As[(kloc + 1) * SA + lm] = a4.y;
            As[(kloc + 2) * SA + lm] = a4.z;
            As[(kloc + 3) * SA + lm] = a4.w;
        }
        // ---- stage W tile: Ws[k][e]; global reads coalesced (256B/k-row)
#pragma unroll
        for (int i = 0; i < 2; ++i) {
            const int kr = wkr + 16 * i;            // 0..31
            const float4 w4 = *(const float4*)(Bw + (size_t)(k0 + kr) * EXP + 4 * weq);
            *(float4*)(&Ws[kr * SW + 4 * weq]) = w4;
        }
        __syncthreads();

        float facc[4][4] = {{0.f,0.f,0.f,0.f},{0.f,0.f,0.f,0.f},
                            {0.f,0.f,0.f,0.f},{0.f,0.f,0.f,0.f}};
#pragma unroll 8
        for (int k = 0; k < BK; ++k) {
            const float4 a4 = *(const float4*)(&As[k * SA + (ty << 2)]);
            const float4 w4 = *(const float4*)(&Ws[k * SW + (tx << 2)]);
            const float av[4] = {a4.x, a4.y, a4.z, a4.w};
            const float wv[4] = {w4.x, w4.y, w4.z, w4.w};
#pragma unroll
            for (int i = 0; i < 4; ++i)
#pragma unroll
                for (int j = 0; j < 4; ++j)
                    facc[i][j] = fmaf(av[i], wv[j], facc[i][j]);
        }
        // drain fp32 chunk into f64 master accumulators (precision: ~1e-7 total)
#pragma unroll
        for (int i = 0; i < 4; ++i)
#pragma unroll
            for (int j = 0; j < 4; ++j) acc[i][j] += (double)facc[i][j];
        __syncthreads();
    }

#pragma unroll
    for (int i = 0; i < 4; ++i) {
        const int row = rowBase + (ty << 2) + i;
#pragma unroll
        for (int j = 0; j < 4; ++j)
            out[(size_t)row * EXP + (tx << 2) + j] = (float)acc[i][j];
    }
}

// one wave per row: logits = p0+p1; top-2 (jax tie-break: lower index wins);
// gates = softmax over the two top logits (equals renormalized full softmax).
__global__ __launch_bounds__(256) void topk_epilogue(
    const float* __restrict__ p0, const float* __restrict__ p1,
    float* __restrict__ outv)
{
    const int tid  = threadIdx.x;
    const int lane = tid & 63;
    const int row  = blockIdx.x * 4 + (tid >> 6);

    const float logit = p0[(size_t)row * EXP + lane] + p1[(size_t)row * EXP + lane];

    float v = logit; int idx = lane;
#pragma unroll
    for (int off = 32; off >= 1; off >>= 1) {
        const float vo = __shfl_xor(v, off, 64);
        const int   io = __shfl_xor(idx, off, 64);
        if (vo > v || (vo == v && io < idx)) { v = vo; idx = io; }
    }
    const float v1 = v; const int i1 = idx;

    float v2 = (lane == i1) ? -INFINITY : logit; int idx2 = lane;
#pragma unroll
    for (int off = 32; off >= 1; off >>= 1) {
        const float vo = __shfl_xor(v2, off, 64);
        const int   io = __shfl_xor(idx2, off, 64);
        if (vo > v2 || (vo == v2 && io < idx2)) { v2 = vo; idx2 = io; }
    }

    if (lane == 0) {
        const float e2 = expf(v2 - v1);       // <= 1
        const float g1 = 1.0f / (1.0f + e2);
        const float g2 = e2 * g1;
        outv[(size_t)row * 2 + 0] = g1;
        outv[(size_t)row * 2 + 1] = g2;
        outv[(size_t)2 * M_TOTAL + row * 2 + 0] = (float)i1;
        outv[(size_t)2 * M_TOTAL + row * 2 + 1] = (float)idx2;
    }
}

extern "C" void kernel_launch(void* const* d_in, const int* in_sizes, int n_in,
                              void* d_out, int out_size, void* d_ws, size_t ws_size,
                              hipStream_t stream)
{
    const float* x     = (const float*)d_in[0];
    const float* noise = (const float*)d_in[1];
    const float* w     = (const float*)d_in[2];
    const float* nw    = (const float*)d_in[3];
    // d_in[4] = top_k (==2), compile-time assumed

    float* ws = (float*)d_ws;
    float* p0 = ws;                                  // [16384][64]
    float* p1 = ws + (size_t)M_TOTAL * EXP;          // [16384][64]

    dim3 grid(M_TOTAL / BM, 2);                      // 256 row-blocks x 2 slices
    router_gemm<<<grid, 256, 0, stream>>>(x, noise, w, nw, p0);
    topk_epilogue<<<M_TOTAL / 4, 256, 0, stream>>>(p0, p1, (float*)d_out);
}

// Round 2
// 404.729 us; speedup vs baseline: 1.1905x; 1.1905x over previous
//
#include <hip/hip_runtime.h>
#include <math.h>

#define M_TOTAL 16384
#define DDIM    4096
#define EXP     64
#define BM      128
#define BK      16
#define SM      132   // padded LDS row stride (words): staging writes 2-way (free), reads conflict-free

// part[ks][row][e] = sum_{k in ks-range} ( x[row][k]*w[k][e] + noise[row][k]*nw[k][e] )
// 256 threads = 4 waves; wave owns 16 experts (SGPR W), lane owns 2 rows (LDS A broadcast).
template<int KSPLIT>
__global__ __launch_bounds__(256) void router_gemm2(
    const float* __restrict__ x, const float* __restrict__ noise,
    const float* __restrict__ w, const float* __restrict__ nw,
    float* __restrict__ part)
{
    constexpr int KRANGE = DDIM / KSPLIT;
    constexpr int NKT    = KRANGE / BK;     // k-tiles per slice

    __shared__ float As[2][BK * SM];

    const int tid  = threadIdx.x;
    const int lane = tid & 63;
    const int e0   = __builtin_amdgcn_readfirstlane((tid >> 6) << 4);  // wave-uniform expert base

    const int rowBase = blockIdx.x * BM;
    const int kBase   = blockIdx.y * KRANGE;

    // staging map: thread loads float4 at (row = mrow + 64*half, k = 4q..4q+3)
    const int q    = tid & 3;
    const int mrow = tid >> 2;

    float  facc[2][16];
    double dacc[2][16];
#pragma unroll
    for (int r = 0; r < 2; ++r)
#pragma unroll
        for (int e = 0; e < 16; ++e) { facc[r][e] = 0.f; dacc[r][e] = 0.0; }

    auto gptr = [&](int t, int half) -> const float* {
        const int s  = t / NKT;             // 0: x@w, 1: noise@nw
        const int kt = t - s * NKT;
        const float* __restrict__ A = s ? noise : x;
        return A + (size_t)(rowBase + mrow + 64 * half) * DDIM + (kBase + kt * BK + 4 * q);
    };

    // ---- preload tile 0
    {
        const float4 r0 = *(const float4*)gptr(0, 0);
        const float4 r1 = *(const float4*)gptr(0, 1);
#pragma unroll
        for (int j = 0; j < 4; ++j) {
            As[0][(4 * q + j) * SM + mrow]      = ((const float*)&r0)[j];
            As[0][(4 * q + j) * SM + mrow + 64] = ((const float*)&r1)[j];
        }
    }
    __syncthreads();

    int cur = 0;
    for (int t = 0; t < 2 * NKT; ++t) {
        // prefetch next tile into registers (hides HBM latency under compute)
        float4 n0, n1;
        const bool more = (t + 1 < 2 * NKT);
        if (more) {
            n0 = *(const float4*)gptr(t + 1, 0);
            n1 = *(const float4*)gptr(t + 1, 1);
        }

        const int s  = t / NKT;
        const int kt = t - s * NKT;
        const float* __restrict__ Wk = (s ? nw : w) + (size_t)(kBase + kt * BK) * EXP + e0;

#pragma unroll
        for (int kk = 0; kk < BK; ++kk) {
            float wv[16];                                   // wave-uniform -> s_load
#pragma unroll
            for (int e = 0; e < 16; ++e) wv[e] = Wk[kk * EXP + e];
            const float2 a2 = *(const float2*)&As[cur][kk * SM + 2 * lane];
#pragma unroll
            for (int e = 0; e < 16; ++e) {
                facc[0][e] = fmaf(a2.x, wv[e], facc[0][e]);
                facc[1][e] = fmaf(a2.y, wv[e], facc[1][e]);
            }
        }

        // drain fp32 chunk (64 k) into f64 masters: total logit error ~1e-7
        if ((t & 3) == 3) {
#pragma unroll
            for (int r = 0; r < 2; ++r)
#pragma unroll
                for (int e = 0; e < 16; ++e) { dacc[r][e] += (double)facc[r][e]; facc[r][e] = 0.f; }
        }

        __syncthreads();            // all waves done reading As[cur^1] (last tile) & As[cur]
        if (more) {
#pragma unroll
            for (int j = 0; j < 4; ++j) {
                As[cur ^ 1][(4 * q + j) * SM + mrow]      = ((const float*)&n0)[j];
                As[cur ^ 1][(4 * q + j) * SM + mrow + 64] = ((const float*)&n1)[j];
            }
        }
        __syncthreads();            // next tile staged
        cur ^= 1;
    }

    // ---- write partial plane (fp32; f64->fp32 rounding ~6e-8 rel)
    float* __restrict__ out = part + (size_t)blockIdx.y * M_TOTAL * EXP
                            + (size_t)(rowBase + 2 * lane) * EXP + e0;
#pragma unroll
    for (int r = 0; r < 2; ++r) {
#pragma unroll
        for (int e4 = 0; e4 < 4; ++e4) {
            float4 o;
            o.x = (float)dacc[r][4 * e4 + 0];
            o.y = (float)dacc[r][4 * e4 + 1];
            o.z = (float)dacc[r][4 * e4 + 2];
            o.w = (float)dacc[r][4 * e4 + 3];
            *(float4*)(out + (size_t)r * EXP + 4 * e4) = o;
        }
    }
}

// one wave per row: logits = sum of partial planes (f64); top-2 (jax tie-break:
// lower index wins); gates = 2-logit softmax == renormalized full softmax.
__global__ __launch_bounds__(256) void topk_epilogue2(
    const float* __restrict__ part, const int nplanes, float* __restrict__ outv)
{
    const int tid  = threadIdx.x;
    const int lane = tid & 63;
    const int row  = blockIdx.x * 4 + (tid >> 6);

    double sd = 0.0;
    for (int p = 0; p < nplanes; ++p)
        sd += (double)part[((size_t)p * M_TOTAL + row) * EXP + lane];
    const float logit = (float)sd;

    float v = logit; int idx = lane;
#pragma unroll
    for (int off = 32; off >= 1; off >>= 1) {
        const float vo = __shfl_xor(v, off, 64);
        const int   io = __shfl_xor(idx, off, 64);
        if (vo > v || (vo == v && io < idx)) { v = vo; idx = io; }
    }
    const float v1 = v; const int i1 = idx;

    float v2 = (lane == i1) ? -INFINITY : logit; int idx2 = lane;
#pragma unroll
    for (int off = 32; off >= 1; off >>= 1) {
        const float vo = __shfl_xor(v2, off, 64);
        const int   io = __shfl_xor(idx2, off, 64);
        if (vo > v2 || (vo == v2 && io < idx2)) { v2 = vo; idx2 = io; }
    }

    if (lane == 0) {
        const float e2 = expf(v2 - v1);       // <= 1
        const float g1 = 1.0f / (1.0f + e2);
        const float g2 = e2 * g1;
        outv[(size_t)row * 2 + 0] = g1;
        outv[(size_t)row * 2 + 1] = g2;
        outv[(size_t)2 * M_TOTAL + row * 2 + 0] = (float)i1;
        outv[(size_t)2 * M_TOTAL + row * 2 + 1] = (float)idx2;
    }
}

extern "C" void kernel_launch(void* const* d_in, const int* in_sizes, int n_in,
                              void* d_out, int out_size, void* d_ws, size_t ws_size,
                              hipStream_t stream)
{
    const float* x     = (const float*)d_in[0];
    const float* noise = (const float*)d_in[1];
    const float* w     = (const float*)d_in[2];
    const float* nw    = (const float*)d_in[3];
    // d_in[4] = top_k (==2), compile-time assumed

    float* part = (float*)d_ws;
    const size_t plane_bytes = (size_t)M_TOTAL * EXP * sizeof(float);

    if (ws_size >= 4 * plane_bytes) {
        dim3 grid(M_TOTAL / BM, 4);
        router_gemm2<4><<<grid, 256, 0, stream>>>(x, noise, w, nw, part);
        topk_epilogue2<<<M_TOTAL / 4, 256, 0, stream>>>(part, 4, (float*)d_out);
    } else {
        dim3 grid(M_TOTAL / BM, 2);
        router_gemm2<2><<<grid, 256, 0, stream>>>(x, noise, w, nw, part);
        topk_epilogue2<<<M_TOTAL / 4, 256, 0, stream>>>(part, 2, (float*)d_out);
    }
}

// Round 3
// 258.345 us; speedup vs baseline: 1.8651x; 1.5666x over previous
//
#include <hip/hip_runtime.h>
#include <math.h>

#define M_TOTAL 16384
#define DDIM    4096
#define EXP     64
#define BM      256
#define BK      16
#define SM      260   // As row stride (words); 260%8==4 -> conflict-free staging + reads

// part[ks][row][e] = sum_{k in plane} ( x[row][k]*w[k][e] + noise[row][k]*nw[k][e] )
// 4 waves; wave = 8x8 lane grid; lane computes 8 rows x 8 experts; both operands LDS.
template<int KSPLIT>
__global__ __launch_bounds__(256, 2) void router_gemm3(
    const float* __restrict__ x, const float* __restrict__ noise,
    const float* __restrict__ w, const float* __restrict__ nw,
    float* __restrict__ part)
{
    constexpr int KRANGE = DDIM / KSPLIT;
    constexpr int NKT    = KRANGE / BK;   // k-tiles per slice
    constexpr int NT     = 2 * NKT;       // both slices fused in-register

    __shared__ float As[2][BK * SM];
    __shared__ float Ws[2][BK * EXP];

    const int tid  = threadIdx.x;
    const int wv_  = tid >> 6;            // wave 0..3 -> row group
    const int lane = tid & 63;
    const int lr   = lane >> 3;           // lane row-octet
    const int lc   = lane & 7;            // lane expert-octet

    const int rowBase = blockIdx.x * BM;
    const int kBase   = blockIdx.y * KRANGE;

    // staging maps
    const int q  = tid & 3,  mr = tid >> 2;   // A: row mr(+64i), k-quad q
    const int kr = tid >> 4, we = tid & 15;   // W: k-row kr, e-quad we

    const int aOff = 64 * wv_ + 8 * lr;       // row offset within block tile
    const int wOff = 8 * lc;                  // expert offset

    float facc[8][8], macc[8][8];
#pragma unroll
    for (int j = 0; j < 8; ++j)
#pragma unroll
        for (int e = 0; e < 8; ++e) { facc[j][e] = 0.f; macc[j][e] = 0.f; }

    auto aload = [&](int t, int i) -> float4 {
        const int s = (t >= NKT) ? 1 : 0;
        const float* __restrict__ A = s ? noise : x;
        const int kt = t - s * NKT;
        return *(const float4*)(A + (size_t)(rowBase + mr + 64 * i) * DDIM
                                  + (kBase + kt * BK + 4 * q));
    };
    auto wload = [&](int t) -> float4 {
        const int s = (t >= NKT) ? 1 : 0;
        const float* __restrict__ Bw = s ? nw : w;
        const int kt = t - s * NKT;
        return *(const float4*)(Bw + (size_t)(kBase + kt * BK + kr) * EXP + 4 * we);
    };

    // ---- preload tile 0
    {
        float4 p0 = aload(0, 0), p1 = aload(0, 1), p2 = aload(0, 2), p3 = aload(0, 3);
        float4 pw = wload(0);
#pragma unroll
        for (int j = 0; j < 4; ++j) {
            As[0][(4 * q + j) * SM + mr      ] = ((const float*)&p0)[j];
            As[0][(4 * q + j) * SM + mr +  64] = ((const float*)&p1)[j];
            As[0][(4 * q + j) * SM + mr + 128] = ((const float*)&p2)[j];
            As[0][(4 * q + j) * SM + mr + 192] = ((const float*)&p3)[j];
        }
        *(float4*)&Ws[0][kr * EXP + 4 * we] = pw;
    }
    __syncthreads();

    int cur = 0;
    for (int t = 0; t < NT; ++t) {
        float4 p0, p1, p2, p3, pw;
        const bool more = (t + 1 < NT);
        if (more) {                        // issue next-tile loads early; land under compute
            p0 = aload(t + 1, 0); p1 = aload(t + 1, 1);
            p2 = aload(t + 1, 2); p3 = aload(t + 1, 3);
            pw = wload(t + 1);
        }

        const float* __restrict__ Ap = &As[cur][aOff];
        const float* __restrict__ Wp = &Ws[cur][wOff];
#pragma unroll 4
        for (int kk = 0; kk < BK; ++kk) {
            const float4 a0 = *(const float4*)(Ap + kk * SM);
            const float4 a1 = *(const float4*)(Ap + kk * SM + 4);
            const float4 w0 = *(const float4*)(Wp + kk * EXP);
            const float4 w1 = *(const float4*)(Wp + kk * EXP + 4);
            const float av[8] = {a0.x, a0.y, a0.z, a0.w, a1.x, a1.y, a1.z, a1.w};
            const float wvv[8] = {w0.x, w0.y, w0.z, w0.w, w1.x, w1.y, w1.z, w1.w};
#pragma unroll
            for (int j = 0; j < 8; ++j)
#pragma unroll
                for (int e = 0; e < 8; ++e)
                    facc[j][e] = fmaf(av[j], wvv[e], facc[j][e]);
        }

        // drain 64-k fp32 chunk into fp32 masters (total plane error ~1e-7)
        if ((t & 3) == 3) {
#pragma unroll
            for (int j = 0; j < 8; ++j)
#pragma unroll
                for (int e = 0; e < 8; ++e) { macc[j][e] += facc[j][e]; facc[j][e] = 0.f; }
        }

        if (more) {                        // write next tile (other buffer: no race)
#pragma unroll
            for (int j = 0; j < 4; ++j) {
                As[cur ^ 1][(4 * q + j) * SM + mr      ] = ((const float*)&p0)[j];
                As[cur ^ 1][(4 * q + j) * SM + mr +  64] = ((const float*)&p1)[j];
                As[cur ^ 1][(4 * q + j) * SM + mr + 128] = ((const float*)&p2)[j];
                As[cur ^ 1][(4 * q + j) * SM + mr + 192] = ((const float*)&p3)[j];
            }
            *(float4*)&Ws[cur ^ 1][kr * EXP + 4 * we] = pw;
        }
        __syncthreads();                   // single barrier per tile (double-buffered)
        cur ^= 1;
    }

    // ---- write partial plane
    float* __restrict__ out = part + (size_t)blockIdx.y * M_TOTAL * EXP;
#pragma unroll
    for (int j = 0; j < 8; ++j) {
        const int row = rowBase + aOff + j;
        float4 o0, o1;
        o0.x = macc[j][0]; o0.y = macc[j][1]; o0.z = macc[j][2]; o0.w = macc[j][3];
        o1.x = macc[j][4]; o1.y = macc[j][5]; o1.z = macc[j][6]; o1.w = macc[j][7];
        *(float4*)(out + (size_t)row * EXP + wOff    ) = o0;
        *(float4*)(out + (size_t)row * EXP + wOff + 4) = o1;
    }
}

// one wave per row: logits = f64 sum of planes; top-2 (jax tie-break: lower index
// wins); gates = 2-logit softmax == renormalized full softmax.
__global__ __launch_bounds__(256) void topk_epilogue3(
    const float* __restrict__ part, const int nplanes, float* __restrict__ outv)
{
    const int tid  = threadIdx.x;
    const int lane = tid & 63;
    const int row  = blockIdx.x * 4 + (tid >> 6);

    double sd = 0.0;
    for (int p = 0; p < nplanes; ++p)
        sd += (double)part[((size_t)p * M_TOTAL + row) * EXP + lane];
    const float logit = (float)sd;

    float v = logit; int idx = lane;
#pragma unroll
    for (int off = 32; off >= 1; off >>= 1) {
        const float vo = __shfl_xor(v, off, 64);
        const int   io = __shfl_xor(idx, off, 64);
        if (vo > v || (vo == v && io < idx)) { v = vo; idx = io; }
    }
    const float v1 = v; const int i1 = idx;

    float v2 = (lane == i1) ? -INFINITY : logit; int idx2 = lane;
#pragma unroll
    for (int off = 32; off >= 1; off >>= 1) {
        const float vo = __shfl_xor(v2, off, 64);
        const int   io = __shfl_xor(idx2, off, 64);
        if (vo > v2 || (vo == v2 && io < idx2)) { v2 = vo; idx2 = io; }
    }

    if (lane == 0) {
        const float e2 = expf(v2 - v1);       // <= 1
        const float g1 = 1.0f / (1.0f + e2);
        const float g2 = e2 * g1;
        outv[(size_t)row * 2 + 0] = g1;
        outv[(size_t)row * 2 + 1] = g2;
        outv[(size_t)2 * M_TOTAL + row * 2 + 0] = (float)i1;
        outv[(size_t)2 * M_TOTAL + row * 2 + 1] = (float)idx2;
    }
}

extern "C" void kernel_launch(void* const* d_in, const int* in_sizes, int n_in,
                              void* d_out, int out_size, void* d_ws, size_t ws_size,
                              hipStream_t stream)
{
    const float* x     = (const float*)d_in[0];
    const float* noise = (const float*)d_in[1];
    const float* w     = (const float*)d_in[2];
    const float* nw    = (const float*)d_in[3];
    // d_in[4] = top_k (==2), compile-time assumed

    float* part = (float*)d_ws;
    const size_t plane_bytes = (size_t)M_TOTAL * EXP * sizeof(float);

    if (ws_size >= 8 * plane_bytes) {
        dim3 grid(M_TOTAL / BM, 8);                    // 512 blocks: 2/CU
        router_gemm3<8><<<grid, 256, 0, stream>>>(x, noise, w, nw, part);
        topk_epilogue3<<<M_TOTAL / 4, 256, 0, stream>>>(part, 8, (float*)d_out);
    } else if (ws_size >= 4 * plane_bytes) {
        dim3 grid(M_TOTAL / BM, 4);
        router_gemm3<4><<<grid, 256, 0, stream>>>(x, noise, w, nw, part);
        topk_epilogue3<<<M_TOTAL / 4, 256, 0, stream>>>(part, 4, (float*)d_out);
    } else {
        dim3 grid(M_TOTAL / BM, 2);
        router_gemm3<2><<<grid, 256, 0, stream>>>(x, noise, w, nw, part);
        topk_epilogue3<<<M_TOTAL / 4, 256, 0, stream>>>(part, 2, (float*)d_out);
    }
}

// Round 4
// 158.092 us; speedup vs baseline: 3.0478x; 1.6341x over previous
//
#include <hip/hip_runtime.h>
#include <math.h>
#include <stdint.h>

#define M_TOTAL 16384
#define DDIM    4096
#define EXP     64

typedef __attribute__((ext_vector_type(8)))  short bf16x8;
typedef __attribute__((ext_vector_type(16))) float f32x16;

__device__ inline uint32_t fbits(float f){ union{float f;uint32_t u;}c; c.f=f; return c.u; }
__device__ inline float    bitsf(uint32_t u){ union{uint32_t u;float f;}c; c.u=u; return c.f; }
__device__ inline bf16x8   asfrag(uint4 t){ return __builtin_bit_cast(bf16x8, t); }

// ---------------------------------------------------------------------------
// W pre-pack: split w/nw into 3 bf16 planes (truncation split, exact to 2^-24)
// stored in MFMA-B-fragment-linear order:
//   word index = (((s*256 + ktile)*2 + ntile)*3 + plane)*256 + lane*4 + j
//   where lane = (e&31) + 32*((k>>3)&1), elem i = k&7, word j holds elems 2j,2j+1
// ---------------------------------------------------------------------------
__global__ __launch_bounds__(256) void wpack_prep(
    const float* __restrict__ w, const float* __restrict__ nw,
    uint32_t* __restrict__ wpack)
{
    const int t = blockIdx.x * 256 + threadIdx.x;     // 786432 words total
    const int jw   = t & 3;
    const int lane = (t >> 2) & 63;
    const int rest = t >> 8;                          // ((s*256+kt)*2+nt)*3+pl
    const int pl   = rest % 3;
    const int r2   = rest / 3;
    const int nt   = r2 & 1;
    const int kt   = (r2 >> 1) & 255;
    const int s    = r2 >> 9;

    const int k0 = kt * 16 + (lane >> 5) * 8 + 2 * jw;
    const int e  = nt * 32 + (lane & 31);
    const float* __restrict__ src = s ? nw : w;
    float f0 = src[(size_t)k0 * EXP + e];
    float f1 = src[(size_t)(k0 + 1) * EXP + e];
    uint32_t u0 = fbits(f0), u1 = fbits(f1);
    for (int l = 0; l < pl; ++l) {                    // peel to level pl
        f0 -= bitsf(u0 & 0xFFFF0000u);
        f1 -= bitsf(u1 & 0xFFFF0000u);
        u0 = fbits(f0); u1 = fbits(f1);
    }
    wpack[t] = (u0 >> 16) | (u1 & 0xFFFF0000u);       // [lo=elem2j, hi=elem2j+1]
}

// ---------------------------------------------------------------------------
// MFMA GEMM: part[kp][row][e] = sum over k-plane of (x@w + noise@nw)
// block = 4 waves, BM=256 (wave tile 64 rows x 64 experts = 2m x 2n MFMA tiles)
// A: global->reg, split in-register to 3 bf16 frags. W: LDS chunks (frag-linear).
// ---------------------------------------------------------------------------
template<int KSPLIT>
__global__ __launch_bounds__(256, 2) void router_mfma(
    const float* __restrict__ x, const float* __restrict__ noise,
    const uint32_t* __restrict__ wpack, float* __restrict__ part)
{
    constexpr int KRANGE = DDIM / KSPLIT;   // k per plane
    constexpr int VPS    = KRANGE / 16;     // ksteps per slice
    constexpr int NU     = 2 * VPS;         // ksteps total (both slices)
    constexpr int CPS    = VPS / 4;         // chunks per slice
    constexpr int NCHUNK = 2 * CPS;         // chunks total (64 k each)

    __shared__ uint32_t Wl[2][6144];        // 2 x 24 KB, frag-linear

    const int tid  = threadIdx.x;
    const int w_   = tid >> 6;
    const int lane = tid & 63;
    const int l31  = lane & 31;
    const int kh   = lane >> 5;             // k-half of the fragment

    const int rowBase = blockIdx.x * 256 + w_ * 64;
    const int kp      = blockIdx.y;

    const size_t ro[2] = { (size_t)(rowBase      + l31) * DDIM,
                           (size_t)(rowBase + 32 + l31) * DDIM };

    f32x16 acc[2][2], macc[2][2];
#pragma unroll
    for (int a = 0; a < 2; ++a)
#pragma unroll
        for (int b = 0; b < 2; ++b)
#pragma unroll
            for (int i = 0; i < 16; ++i) { acc[a][b][i] = 0.f; macc[a][b][i] = 0.f; }

    auto stage = [&](int cc, int buf) {     // stage one 24 KB W chunk into LDS
        const int s = cc / CPS, c = cc % CPS;
        const uint32_t* gp = wpack + (size_t)(s * 256 + kp * VPS + c * 4) * 1536;
#pragma unroll
        for (int j = 0; j < 6; ++j) {
            const int off = j * 1024 + tid * 4;
            __builtin_amdgcn_global_load_lds(
                (const __attribute__((address_space(1))) uint32_t*)(gp + off),
                (__attribute__((address_space(3))) uint32_t*)(&Wl[buf][off]),
                16, 0, 0);
        }
    };

    auto aload = [&](int u, float4* dst) {  // raw A (8 f32/lane/mtile) for kstep u
        const int s = u / VPS, v = u % VPS;
        const float* __restrict__ base = s ? noise : x;
        const size_t ko = (size_t)(kp * KRANGE + v * 16 + kh * 8);
#pragma unroll
        for (int mt = 0; mt < 2; ++mt) {
            dst[2 * mt]     = *(const float4*)(base + ro[mt] + ko);
            dst[2 * mt + 1] = *(const float4*)(base + ro[mt] + ko + 4);
        }
    };

    // prologue
    float4 ap[4];
    stage(0, 0);
    aload(0, ap);
    __syncthreads();                        // Wl[0] ready (barrier drains vmcnt)

    int buf = 0;
    for (int cc = 0; cc < NCHUNK; ++cc) {
        if (cc + 1 < NCHUNK) stage(cc + 1, buf ^ 1);
#pragma unroll
        for (int q = 0; q < 4; ++q) {
            const int u = cc * 4 + q;
            float4 an[4];
            if (u + 1 < NU) aload(u + 1, an);

            // split A -> 3 bf16 fragments per m-tile (truncation split, exact)
            uint32_t fa1[2][4], fa2[2][4], fa3[2][4];
#pragma unroll
            for (int mt = 0; mt < 2; ++mt) {
                const float in[8] = { ap[2*mt].x, ap[2*mt].y, ap[2*mt].z, ap[2*mt].w,
                                      ap[2*mt+1].x, ap[2*mt+1].y, ap[2*mt+1].z, ap[2*mt+1].w };
#pragma unroll
                for (int j = 0; j < 4; ++j) {
                    const float a = in[2*j], b = in[2*j+1];
                    const uint32_t ua = fbits(a), ub = fbits(b);
                    const uint32_t ha = ua & 0xFFFF0000u, hb = ub & 0xFFFF0000u;
                    fa1[mt][j] = (ha >> 16) | hb;
                    const float ra = a - bitsf(ha), rb = b - bitsf(hb);
                    const uint32_t ua2 = fbits(ra), ub2 = fbits(rb);
                    const uint32_t ha2 = ua2 & 0xFFFF0000u, hb2 = ub2 & 0xFFFF0000u;
                    fa2[mt][j] = (ha2 >> 16) | hb2;
                    const float sa = ra - bitsf(ha2), sb = rb - bitsf(hb2);
                    fa3[mt][j] = (fbits(sa) >> 16) | (fbits(sb) & 0xFFFF0000u);
                }
            }

            const uint32_t* wbase = &Wl[buf][q * 1536 + lane * 4];
#pragma unroll
            for (int nt = 0; nt < 2; ++nt) {
                const bf16x8 b1 = asfrag(*(const uint4*)(wbase + nt * 768));
                const bf16x8 b2 = asfrag(*(const uint4*)(wbase + nt * 768 + 256));
                const bf16x8 b3 = asfrag(*(const uint4*)(wbase + nt * 768 + 512));
#pragma unroll
                for (int mt = 0; mt < 2; ++mt) {
                    const bf16x8 a1 = asfrag(*(const uint4*)fa1[mt]);
                    const bf16x8 a2 = asfrag(*(const uint4*)fa2[mt]);
                    const bf16x8 a3 = asfrag(*(const uint4*)fa3[mt]);
                    f32x16 c = acc[mt][nt];
                    c = __builtin_amdgcn_mfma_f32_32x32x16_bf16(a1, b3, c, 0, 0, 0);
                    c = __builtin_amdgcn_mfma_f32_32x32x16_bf16(a3, b1, c, 0, 0, 0);
                    c = __builtin_amdgcn_mfma_f32_32x32x16_bf16(a2, b2, c, 0, 0, 0);
                    c = __builtin_amdgcn_mfma_f32_32x32x16_bf16(a1, b2, c, 0, 0, 0);
                    c = __builtin_amdgcn_mfma_f32_32x32x16_bf16(a2, b1, c, 0, 0, 0);
                    c = __builtin_amdgcn_mfma_f32_32x32x16_bf16(a1, b1, c, 0, 0, 0);
                    acc[mt][nt] = c;
                }
            }
#pragma unroll
            for (int i = 0; i < 4; ++i) ap[i] = an[i];
        }
        // drain 64-k window into fp32 masters (keeps per-add magnitudes small)
#pragma unroll
        for (int a = 0; a < 2; ++a)
#pragma unroll
            for (int b = 0; b < 2; ++b)
#pragma unroll
                for (int i = 0; i < 16; ++i) { macc[a][b][i] += acc[a][b][i]; acc[a][b][i] = 0.f; }
        __syncthreads();                    // next W chunk staged (vmcnt drained)
        buf ^= 1;
    }

    // write plane; C/D layout (HW-verified): col=lane&31, row=(r&3)+8*(r>>2)+4*(lane>>5)
    float* __restrict__ out = part + (size_t)blockIdx.y * M_TOTAL * EXP;
#pragma unroll
    for (int mt = 0; mt < 2; ++mt)
#pragma unroll
        for (int nt = 0; nt < 2; ++nt)
#pragma unroll
            for (int r = 0; r < 16; ++r) {
                const int row = rowBase + mt * 32 + (r & 3) + 8 * (r >> 2) + 4 * kh;
                out[(size_t)row * EXP + nt * 32 + l31] = macc[mt][nt][r];
            }
}

// one wave per row: logits = f64 sum of planes; top-2 (jax tie-break: lower index
// wins); gates = 2-logit softmax == renormalized full softmax.
__global__ __launch_bounds__(256) void topk_epilogue3(
    const float* __restrict__ part, const int nplanes, float* __restrict__ outv)
{
    const int tid  = threadIdx.x;
    const int lane = tid & 63;
    const int row  = blockIdx.x * 4 + (tid >> 6);

    double sd = 0.0;
    for (int p = 0; p < nplanes; ++p)
        sd += (double)part[((size_t)p * M_TOTAL + row) * EXP + lane];
    const float logit = (float)sd;

    float v = logit; int idx = lane;
#pragma unroll
    for (int off = 32; off >= 1; off >>= 1) {
        const float vo = __shfl_xor(v, off, 64);
        const int   io = __shfl_xor(idx, off, 64);
        if (vo > v || (vo == v && io < idx)) { v = vo; idx = io; }
    }
    const float v1 = v; const int i1 = idx;

    float v2 = (lane == i1) ? -INFINITY : logit; int idx2 = lane;
#pragma unroll
    for (int off = 32; off >= 1; off >>= 1) {
        const float vo = __shfl_xor(v2, off, 64);
        const int   io = __shfl_xor(idx2, off, 64);
        if (vo > v2 || (vo == v2 && io < idx2)) { v2 = vo; idx2 = io; }
    }

    if (lane == 0) {
        const float e2 = expf(v2 - v1);       // <= 1
        const float g1 = 1.0f / (1.0f + e2);
        const float g2 = e2 * g1;
        outv[(size_t)row * 2 + 0] = g1;
        outv[(size_t)row * 2 + 1] = g2;
        outv[(size_t)2 * M_TOTAL + row * 2 + 0] = (float)i1;
        outv[(size_t)2 * M_TOTAL + row * 2 + 1] = (float)idx2;
    }
}

extern "C" void kernel_launch(void* const* d_in, const int* in_sizes, int n_in,
                              void* d_out, int out_size, void* d_ws, size_t ws_size,
                              hipStream_t stream)
{
    const float* x     = (const float*)d_in[0];
    const float* noise = (const float*)d_in[1];
    const float* w     = (const float*)d_in[2];
    const float* nw    = (const float*)d_in[3];
    // d_in[4] = top_k (==2), compile-time assumed

    const size_t plane_bytes = (size_t)M_TOTAL * EXP * sizeof(float);
    const size_t wpack_bytes = (size_t)786432 * 4;
    float* part = (float*)d_ws;

    if (ws_size >= 8 * plane_bytes + wpack_bytes) {
        uint32_t* wpack = (uint32_t*)((char*)d_ws + 8 * plane_bytes);
        wpack_prep<<<3072, 256, 0, stream>>>(w, nw, wpack);
        router_mfma<8><<<dim3(64, 8), 256, 0, stream>>>(x, noise, wpack, part);
        topk_epilogue3<<<M_TOTAL / 4, 256, 0, stream>>>(part, 8, (float*)d_out);
    } else if (ws_size >= 4 * plane_bytes + wpack_bytes) {
        uint32_t* wpack = (uint32_t*)((char*)d_ws + 4 * plane_bytes);
        wpack_prep<<<3072, 256, 0, stream>>>(w, nw, wpack);
        router_mfma<4><<<dim3(64, 4), 256, 0, stream>>>(x, noise, wpack, part);
        topk_epilogue3<<<M_TOTAL / 4, 256, 0, stream>>>(part, 4, (float*)d_out);
    } else {
        uint32_t* wpack = (uint32_t*)((char*)d_ws + 2 * plane_bytes);
        wpack_prep<<<3072, 256, 0, stream>>>(w, nw, wpack);
        router_mfma<2><<<dim3(64, 2), 256, 0, stream>>>(x, noise, wpack, part);
        topk_epilogue3<<<M_TOTAL / 4, 256, 0, stream>>>(part, 2, (float*)d_out);
    }
}